// Round 4
// baseline (937.169 us; speedup 1.0000x reference)
//
#include <hip/hip_runtime.h>
#include <hip/hip_bf16.h>

#define T_STEPS 2048
#define BATCH   256
#define DIM     128
#define INV2PI  0.15915494309189535f

// ---------------------------------------------------------------------------
// prep: pack weights Wc[d*16 + (g*4+k)] = W_g[d*4+k] * (1/2pi),
//       bt[u] = (b_g[k]+theta_g[k]) * (1/2pi).
// z only ever feeds cos(2*pi*fract(.)), so prescaling W,b,theta (not h)
// by 1/2pi is exact up to fp rounding and removes a mul from the chain.
// ---------------------------------------------------------------------------
__global__ __launch_bounds__(64) void prep(
    const float* __restrict__ Wf, const float* __restrict__ bf, const float* __restrict__ tf,
    const float* __restrict__ Wi, const float* __restrict__ bi, const float* __restrict__ ti,
    const float* __restrict__ Wu, const float* __restrict__ bu, const float* __restrict__ tu,
    const float* __restrict__ Wo, const float* __restrict__ bo, const float* __restrict__ to_,
    float* __restrict__ Wc, float* __restrict__ bt)
{
    const int tid = threadIdx.x;
    for (int idx = tid; idx < DIM * 16; idx += 64) {
        int d = idx >> 4, u = idx & 15, g = u >> 2, k = u & 3;
        const float* W = (g == 0) ? Wf : (g == 1) ? Wi : (g == 2) ? Wu : Wo;
        Wc[idx] = W[d * 4 + k] * INV2PI;
    }
    if (tid < 16) {
        int g = tid >> 2, k = tid & 3;
        const float* bb = (g == 0) ? bf : (g == 1) ? bi : (g == 2) ? bu : bo;
        const float* tt = (g == 0) ? tf : (g == 1) ? ti : (g == 2) ? tu : to_;
        bt[tid] = (bb[k] + tt[k]) * INV2PI;
    }
}

// ---------------------------------------------------------------------------
// Fused recurrence (v5): the standalone zx_gemm pass (~300 us, hidden just
// below qlstm_rec's 298 in top-k) is deleted. The x-projection rides in the
// recurrence chain's stall cycles instead:
//  - 1 batch per wave (256 blocks x 64 thr, all 256 CUs active).
//  - lane (q=tid>>4, u=tid&15) holds quarter-column weights wq[32] (VGPR)
//    and computes a partial z over d in [32q, 32q+32): 32 FMA/lane/step.
//  - cross-row reduce via 2x __shfl_xor (+32,+16); all off the h-chain:
//    zx for step t+1 is computed during step t's chain.
//  - x staged in 32-step LDS windows, padded [4 quarters][9 chunks] layout
//    (576 B/step): read banks (16s + 4q + 4j) % 32 -> the 4 row addresses
//    are disjoint 16-bank spans => conflict-free broadcast ds_read_b128.
//  - window w+1 global loads issue at window-w start; ds_writes happen
//    mid-window (vmcnt long satisfied -> no stall bubble).
// ---------------------------------------------------------------------------
template<int CTRL>
__device__ __forceinline__ float fdpp(float x) {
    return __int_as_float(__builtin_amdgcn_update_dpp(
        0, __float_as_int(x), CTRL, 0xF, 0xF, true));
}

__device__ __forceinline__ float lstm_step(
    float& h, float& c, float zb,
    float wh0, float wh1, float wh2, float wh3,
    float s1c, float m2, float m3, int k, bool b0g, bool b1g)
{
    float h0 = fdpp<0x00>(h), h1 = fdpp<0x55>(h), h2 = fdpp<0xAA>(h), h3 = fdpp<0xFF>(h);
    float t1 = fmaf(h2, wh2, h3 * wh3);
    float z  = fmaf(h1, wh1, fmaf(h0, wh0, zb)) + t1;   // in revolutions

    float cs = __builtin_amdgcn_cosf(__builtin_amdgcn_fractf(z));

    float q0 = fdpp<0x00>(cs), q1 = fdpp<0x55>(cs), q2 = fdpp<0xAA>(cs);
    float p = (q0 * (k >= 1 ? q1 : 1.f)) * ((k >= 2 ? q2 : 1.f) * (k == 3 ? cs : 1.f));

    float e = __builtin_amdgcn_exp2f(p * s1c);
    float y = fmaf(__builtin_amdgcn_rcpf(1.f + e), m2, m3);

    float mm  = fdpp<0x1B>(y);
    float y4  = fdpp<0x141>(mm);
    float y8  = fdpp<0x128>(y);
    float y12 = fdpp<0x128>(y4);
    float t01  = b0g ? y4  : y,  t01s = b0g ? y  : y4;
    float t23  = b0g ? y12 : y8, t23s = b0g ? y8 : y12;
    float fv = b1g ? t23  : t01;
    float iv = b1g ? t23s : t01s;
    float gv = b1g ? t01  : t23;
    float ov = b1g ? t01s : t23s;

    c = fmaf(fv, c, iv * gv);
    float e2 = __builtin_amdgcn_exp2f(c * -2.885390082f);
    float th = fmaf(2.f, __builtin_amdgcn_rcpf(1.f + e2), -1.f);
    h = ov * th;
    return h;
}

__global__ __launch_bounds__(64) void qlstm_fused(
    const float4* __restrict__ x4,
    const float*  __restrict__ Wc,    // [128][16] packed, prescaled
    const float*  __restrict__ btv,   // [16] prescaled
    const float* __restrict__ Wf, const float* __restrict__ Wi,
    const float* __restrict__ Wu, const float* __restrict__ Wo,
    float* __restrict__ out)
{
    __shared__ float xbuf[2][32 * 144];   // 2 x 18432 B (32 steps, 576 B each)

    const int tid = threadIdx.x;
    const int q   = tid >> 4;      // d-quarter this lane accumulates
    const int u   = tid & 15;      // output unit (g*4+k)
    const int g   = u >> 2;
    const int k   = u & 3;
    const int b   = blockIdx.x;    // one batch per block/wave

    // per-lane quarter-column of prescaled Wc: w for d = q*32 + dd
    float wq[32];
#pragma unroll
    for (int dd = 0; dd < 32; ++dd) wq[dd] = Wc[(q * 32 + dd) * 16 + u];
    const float btu = btv[u];

    const float* Wg = (g == 0) ? Wf : (g == 1) ? Wi : (g == 2) ? Wu : Wo;
    const float wh0 = Wg[(DIM + 0) * 4 + k] * INV2PI;
    const float wh1 = Wg[(DIM + 1) * 4 + k] * INV2PI;
    const float wh2 = Wg[(DIM + 2) * 4 + k] * INV2PI;
    const float wh3 = Wg[(DIM + 3) * 4 + k] * INV2PI;

    const bool  isg = (g == 2);
    const float s1c = isg ? -2.885390082f : -1.442695041f;
    const float m2  = isg ? 2.f : 1.f;
    const float m3  = isg ? -1.f : 0.f;
    const bool  b0g = (g & 1) != 0;
    const bool  b1g = (g & 2) != 0;

    const bool do_store = (tid < 4);          // row 0, g=0 -> k = tid
    float* op = out + b * 4 + k;

    float h = 0.f, c = 0.f;
    int pb = 0;

    float4 sx[16];                            // staging regs (held half-window)

    auto stage_load = [&](int w) {
        const int t0 = w * 32;
#pragma unroll
        for (int m = 0; m < 16; ++m) {
            int G = m * 64 + tid, s = G >> 5, cc = G & 31;
            sx[m] = x4[((size_t)(t0 + s) * BATCH + b) * 32 + cc];
        }
    };
    auto stage_write = [&](int dst) {
#pragma unroll
        for (int m = 0; m < 16; ++m) {
            int G = m * 64 + tid, s = G >> 5, cc = G & 31;
            *(float4*)&xbuf[dst][s * 144 + (cc >> 3) * 36 + (cc & 7) * 4] = sx[m];
        }
    };
    // partial x-projection for this lane's quarter, then wave-reduce
    auto zx_full = [&](int slot, int buf) -> float {
        const float* xp = &xbuf[buf][slot * 144 + q * 36];
        float a0 = 0.f, a1 = 0.f;
#pragma unroll
        for (int j = 0; j < 8; j += 2) {
            float4 xa = *(const float4*)&xp[j * 4];
            float4 xb = *(const float4*)&xp[j * 4 + 4];
            a0 = fmaf(xa.x, wq[4 * j + 0], a0);
            a0 = fmaf(xa.y, wq[4 * j + 1], a0);
            a0 = fmaf(xa.z, wq[4 * j + 2], a0);
            a0 = fmaf(xa.w, wq[4 * j + 3], a0);
            a1 = fmaf(xb.x, wq[4 * j + 4], a1);
            a1 = fmaf(xb.y, wq[4 * j + 5], a1);
            a1 = fmaf(xb.z, wq[4 * j + 6], a1);
            a1 = fmaf(xb.w, wq[4 * j + 7], a1);
        }
        float v = a0 + a1;
        v += __shfl_xor(v, 32);
        v += __shfl_xor(v, 16);
        return v + btu;
    };

    // prologue: window 0 staged immediately (one-time vmcnt stall)
    stage_load(0);
    stage_write(0);
    float zxc = zx_full(0, 0);

    for (int w = 0; w < 64; ++w) {
        if (w < 63) stage_load(w + 1);
#pragma unroll 4
        for (int s = 0; s < 16; ++s) {
            float zxn = zx_full(s + 1, pb);
            float o = lstm_step(h, c, zxc, wh0, wh1, wh2, wh3, s1c, m2, m3, k, b0g, b1g);
            if (do_store) op[(size_t)(w * 32 + s) * (BATCH * 4)] = o;
            zxc = zxn;
        }
        if (w < 63) stage_write(pb ^ 1);      // vmcnt satisfied by 16 steps of work
#pragma unroll 3
        for (int s = 16; s < 31; ++s) {
            float zxn = zx_full(s + 1, pb);
            float o = lstm_step(h, c, zxc, wh0, wh1, wh2, wh3, s1c, m2, m3, k, b0g, b1g);
            if (do_store) op[(size_t)(w * 32 + s) * (BATCH * 4)] = o;
            zxc = zxn;
        }
        {   // s = 31: next zx comes from the freshly staged other buffer
            float zxn = zx_full(0, pb ^ 1);   // w=63: in-bounds garbage, unused
            float o = lstm_step(h, c, zxc, wh0, wh1, wh2, wh3, s1c, m2, m3, k, b0g, b1g);
            if (do_store) op[(size_t)(w * 32 + 31) * (BATCH * 4)] = o;
            zxc = zxn;
        }
        pb ^= 1;
    }

    if (do_store) {
        size_t hx_off = (size_t)T_STEPS * BATCH * 4;
        out[hx_off + b * 4 + k] = h;
        out[hx_off + BATCH * 4 + b * 4 + k] = c;
    }
}

extern "C" void kernel_launch(void* const* d_in, const int* in_sizes, int n_in,
                              void* d_out, int out_size, void* d_ws, size_t ws_size,
                              hipStream_t stream) {
    const float* x  = (const float*)d_in[0];
    const float* Wf = (const float*)d_in[1];
    const float* bf = (const float*)d_in[2];
    const float* tf = (const float*)d_in[3];
    const float* Wi = (const float*)d_in[4];
    const float* bi = (const float*)d_in[5];
    const float* ti = (const float*)d_in[6];
    const float* Wu = (const float*)d_in[7];
    const float* bu = (const float*)d_in[8];
    const float* tu = (const float*)d_in[9];
    const float* Wo = (const float*)d_in[10];
    const float* bo = (const float*)d_in[11];
    const float* to_ = (const float*)d_in[12];
    float* out = (float*)d_out;

    float* Wc = (float*)d_ws;          // 8 KB
    float* bt = Wc + DIM * 16;         // 64 B

    prep<<<1, 64, 0, stream>>>(Wf, bf, tf, Wi, bi, ti, Wu, bu, tu, Wo, bo, to_, Wc, bt);

    qlstm_fused<<<BATCH, 64, 0, stream>>>(
        (const float4*)x, Wc, bt, Wf, Wi, Wu, Wo, out);
}

// Round 6
// 721.732 us; speedup vs baseline: 1.2985x; 1.2985x over previous
//
#include <hip/hip_runtime.h>
#include <hip/hip_bf16.h>

#define T_STEPS 2048
#define BATCH   256
#define DIM     128
#define INV2PI  0.15915494309189535f

#define ZX_FLOATS (T_STEPS * BATCH * 16)   // 33.5 MB

// ---------------------------------------------------------------------------
// prep: pack weights Wc[d*16 + (g*4+k)] = W_g[d*4+k] * (1/2pi),
//       bt[u] = (b_g[k]+theta_g[k]) * (1/2pi).
// z only ever feeds cos(2*pi*fract(.)), so prescaling W,b,theta (not h)
// by 1/2pi is exact up to fp rounding and removes a mul from the chain.
// ---------------------------------------------------------------------------
__global__ __launch_bounds__(64) void prep(
    const float* __restrict__ Wf, const float* __restrict__ bf, const float* __restrict__ tf,
    const float* __restrict__ Wi, const float* __restrict__ bi, const float* __restrict__ ti,
    const float* __restrict__ Wu, const float* __restrict__ bu, const float* __restrict__ tu,
    const float* __restrict__ Wo, const float* __restrict__ bo, const float* __restrict__ to_,
    float* __restrict__ Wc, float* __restrict__ bt)
{
    const int tid = threadIdx.x;
    for (int idx = tid; idx < DIM * 16; idx += 64) {
        int d = idx >> 4, u = idx & 15, g = u >> 2, k = u & 3;
        const float* W = (g == 0) ? Wf : (g == 1) ? Wi : (g == 2) ? Wu : Wo;
        Wc[idx] = W[d * 4 + k] * INV2PI;
    }
    if (tid < 16) {
        int g = tid >> 2, k = tid & 3;
        const float* bb = (g == 0) ? bf : (g == 1) ? bi : (g == 2) ? bu : bo;
        const float* tt = (g == 0) ? tf : (g == 1) ? ti : (g == 2) ? tu : to_;
        bt[tid] = (bb[k] + tt[k]) * INV2PI;
    }
}

// ---------------------------------------------------------------------------
// Kernel 1 v6: fixed-overhead analysis across R0/R2/R4 shows gemm was ~105us
// (not ~300): SMEM-stall-bound (per-dd s_load + lgkmcnt(0) drain, unhidden
// at 4 waves/SIMD). v6 makes every hot op throughput-class:
//  - weights in VGPRs: lane (q=lane>>4, u=lane&15) holds wq[32] for its
//    d-quarter, loaded ONCE. No SMEM in the hot loop.
//  - x staged 16 rows/wave in LDS ([16][144] padded layout, measured
//    SQ_LDS_BANK_CONFLICT=0.0 in R4). Reads: 4 distinct b128 addrs/instr
//    (banks disjoint per q) + 16-lane broadcast -> conflict-free.
//  - cross-q reduce: 2x shfl_xor (throughput ops, latency hidden by
//    16 waves/CU), then 4-row-batched 256B coalesced stores.
// Roofline: 268MB read + 33.5MB write ~ 48us; DS-pipe ~54us; SIMD ~30us.
// ---------------------------------------------------------------------------
__global__ __launch_bounds__(256) void zx_gemm(
    const float4* __restrict__ x4,
    const float*  __restrict__ Wc,    // [128][16] packed, prescaled
    const float*  __restrict__ btv,   // [16] prescaled
    float*        __restrict__ Zx)
{
    __shared__ float xs[4][16 * 144];         // 4 x 9216 B = 36864 B/block
    const int lane = threadIdx.x & 63;
    const int wid  = threadIdx.x >> 6;
    float* myxs = xs[wid];

    const int q = lane >> 4;                  // d-quarter
    const int u = lane & 15;                  // output unit

    // per-lane quarter-column of prescaled Wc (one-time load)
    float wq[32];
#pragma unroll
    for (int dd = 0; dd < 32; ++dd) wq[dd] = Wc[(q * 32 + dd) * 16 + u];
    const float btu = btv[u];

    // 1024 blocks x 4 waves: each wave owns 128 consecutive rows (8 x 16)
    const size_t WR0 = ((size_t)blockIdx.x * 4 + wid) * 128;

    float4 sx[8];
    auto stage_load = [&](size_t r0) {
#pragma unroll
        for (int m = 0; m < 8; ++m) {
            int G = m * 64 + lane, s = G >> 5, cc = G & 31;
            sx[m] = x4[(r0 + s) * 32 + cc];   // 1KB contiguous per instr
        }
    };
    auto stage_write = [&]() {
#pragma unroll
        for (int m = 0; m < 8; ++m) {
            int G = m * 64 + lane, s = G >> 5, cc = G & 31;
            *(float4*)&myxs[s * 144 + (cc >> 3) * 36 + (cc & 7) * 4] = sx[m];
        }
    };
    auto zx_row = [&](int r) -> float {       // full z[u] in every lane
        const float* xp = &myxs[r * 144 + q * 36];
        float a0 = 0.f, a1 = 0.f;
#pragma unroll
        for (int j = 0; j < 8; j += 2) {
            float4 xa = *(const float4*)&xp[j * 4];
            float4 xb = *(const float4*)&xp[j * 4 + 4];
            a0 = fmaf(xa.x, wq[4 * j + 0], a0);
            a0 = fmaf(xa.y, wq[4 * j + 1], a0);
            a0 = fmaf(xa.z, wq[4 * j + 2], a0);
            a0 = fmaf(xa.w, wq[4 * j + 3], a0);
            a1 = fmaf(xb.x, wq[4 * j + 4], a1);
            a1 = fmaf(xb.y, wq[4 * j + 5], a1);
            a1 = fmaf(xb.z, wq[4 * j + 6], a1);
            a1 = fmaf(xb.w, wq[4 * j + 7], a1);
        }
        float v = a0 + a1;
        v += __shfl_xor(v, 32);
        v += __shfl_xor(v, 16);
        return v + btu;
    };

    stage_load(WR0);
    stage_write();

    for (int i = 0; i < 8; ++i) {
        const size_t r0 = WR0 + (size_t)i * 16;
        if (i < 7) stage_load(r0 + 16);       // prefetch next chunk into regs

#pragma unroll
        for (int rr = 0; rr < 16; rr += 4) {
            float z0 = zx_row(rr + 0);
            float z1 = zx_row(rr + 1);
            float z2 = zx_row(rr + 2);
            float z3 = zx_row(rr + 3);
            // lane writes element u of row rr+q: 256B contiguous per wave
            float vout = (q == 0) ? z0 : (q == 1) ? z1 : (q == 2) ? z2 : z3;
            Zx[(r0 + rr + q) * 16 + u] = vout;
        }

        if (i < 7) stage_write();             // WAR-safe: after compute; same-wave
                                              // DS in-order, no barrier needed
    }
}

// ---------------------------------------------------------------------------
// Kernel 2 (verbatim R2-measured 298us version): 1 chain per 16-lane group,
// 64 blocks x 64 thr, depth-8 z prefetch. Latency-bound at ~350 cyc/step.
// ---------------------------------------------------------------------------
template<int CTRL>
__device__ __forceinline__ float fdpp(float x) {
    return __int_as_float(__builtin_amdgcn_update_dpp(
        0, __float_as_int(x), CTRL, 0xF, 0xF, true));
}

__device__ __forceinline__ float lstm_step(
    float& h, float& c, float zb,
    float wh0, float wh1, float wh2, float wh3,
    float s1c, float m2, float m3, int k, bool b0g, bool b1g)
{
    float h0 = fdpp<0x00>(h), h1 = fdpp<0x55>(h), h2 = fdpp<0xAA>(h), h3 = fdpp<0xFF>(h);
    float t1 = fmaf(h2, wh2, h3 * wh3);
    float z  = fmaf(h1, wh1, fmaf(h0, wh0, zb)) + t1;   // in revolutions

    float cs = __builtin_amdgcn_cosf(__builtin_amdgcn_fractf(z));

    float q0 = fdpp<0x00>(cs), q1 = fdpp<0x55>(cs), q2 = fdpp<0xAA>(cs);
    float p = (q0 * (k >= 1 ? q1 : 1.f)) * ((k >= 2 ? q2 : 1.f) * (k == 3 ? cs : 1.f));

    float e = __builtin_amdgcn_exp2f(p * s1c);
    float y = fmaf(__builtin_amdgcn_rcpf(1.f + e), m2, m3);

    float mm  = fdpp<0x1B>(y);
    float y4  = fdpp<0x141>(mm);
    float y8  = fdpp<0x128>(y);
    float y12 = fdpp<0x128>(y4);
    float t01  = b0g ? y4  : y,  t01s = b0g ? y  : y4;
    float t23  = b0g ? y12 : y8, t23s = b0g ? y8 : y12;
    float fv = b1g ? t23  : t01;
    float iv = b1g ? t23s : t01s;
    float gv = b1g ? t01  : t23;
    float ov = b1g ? t01s : t23s;

    c = fmaf(fv, c, iv * gv);
    float e2 = __builtin_amdgcn_exp2f(c * -2.885390082f);
    float th = fmaf(2.f, __builtin_amdgcn_rcpf(1.f + e2), -1.f);
    h = ov * th;
    return h;
}

__global__ __launch_bounds__(64) void qlstm_rec(
    const float* __restrict__ Zx,
    const float* __restrict__ Wf, const float* __restrict__ Wi,
    const float* __restrict__ Wu, const float* __restrict__ Wo,
    float* __restrict__ out)
{
    const int tid = threadIdx.x;
    const int u   = tid & 15;
    const int g   = u >> 2;
    const int k   = u & 3;
    const int b   = blockIdx.x * 4 + (tid >> 4);   // 64 blocks x 4 batches

    const float* Wg = (g == 0) ? Wf : (g == 1) ? Wi : (g == 2) ? Wu : Wo;
    const float wh0 = Wg[(DIM + 0) * 4 + k] * INV2PI;
    const float wh1 = Wg[(DIM + 1) * 4 + k] * INV2PI;
    const float wh2 = Wg[(DIM + 2) * 4 + k] * INV2PI;
    const float wh3 = Wg[(DIM + 3) * 4 + k] * INV2PI;

    const bool  isg = (g == 2);
    const float s1c = isg ? -2.885390082f : -1.442695041f;
    const float m2  = isg ? 2.f : 1.f;
    const float m3  = isg ? -1.f : 0.f;
    const bool  b0g = (g & 1) != 0;
    const bool  b1g = (g & 2) != 0;

    const float* zp = Zx + b * 16 + u;      // step stride B*16 = 4096
    const bool do_store = (u < 4);
    float* op = out + b * 4 + k;

    float h = 0.f, c = 0.f;

    float zv[8];
#pragma unroll
    for (int i = 0; i < 8; ++i) zv[i] = zp[(size_t)i * 4096];

    for (int t = 0; t < T_STEPS; t += 8) {
#pragma unroll
        for (int j = 0; j < 8; ++j) {
            int tt = t + j;

            float o = lstm_step(h, c, zv[j], wh0, wh1, wh2, wh3, s1c, m2, m3, k, b0g, b1g);

            if (do_store) op[(size_t)tt * (BATCH * 4)] = o;

            int tn = tt + 8;
            if (tn > T_STEPS - 1) tn = T_STEPS - 1;
            zv[j] = zp[(size_t)tn * 4096];
        }
    }

    if (do_store) {
        size_t hx_off = (size_t)T_STEPS * BATCH * 4;
        out[hx_off + b * 4 + k] = h;
        out[hx_off + BATCH * 4 + b * 4 + k] = c;
    }
}

extern "C" void kernel_launch(void* const* d_in, const int* in_sizes, int n_in,
                              void* d_out, int out_size, void* d_ws, size_t ws_size,
                              hipStream_t stream) {
    const float* x  = (const float*)d_in[0];
    const float* Wf = (const float*)d_in[1];
    const float* bf = (const float*)d_in[2];
    const float* tf = (const float*)d_in[3];
    const float* Wi = (const float*)d_in[4];
    const float* bi = (const float*)d_in[5];
    const float* ti = (const float*)d_in[6];
    const float* Wu = (const float*)d_in[7];
    const float* bu = (const float*)d_in[8];
    const float* tu = (const float*)d_in[9];
    const float* Wo = (const float*)d_in[10];
    const float* bo = (const float*)d_in[11];
    const float* to_ = (const float*)d_in[12];
    float* out = (float*)d_out;

    float* Zx = (float*)d_ws;                       // 33.5 MB
    float* Wc = Zx + ZX_FLOATS;                     // 8 KB
    float* bt = Wc + DIM * 16;                      // 64 B

    prep<<<1, 64, 0, stream>>>(Wf, bf, tf, Wi, bi, ti, Wu, bu, tu, Wo, bo, to_, Wc, bt);

    zx_gemm<<<(T_STEPS * BATCH) / 512, 256, 0, stream>>>(
        (const float4*)x, Wc, bt, Zx);

    qlstm_rec<<<BATCH / 4, 64, 0, stream>>>(Zx, Wf, Wi, Wu, Wo, out);
}